// Round 1
// baseline (183.655 us; speedup 1.0000x reference)
//
#include <hip/hip_runtime.h>

// VisualRetina: strided 32x32 downsample -> Z-order -> per-16-chunk cubic LS fit
// -> [4 coeffs + sigma] channel-mean. One thread per (b, chunk) token.
//
// Z-order decode: chunk n covers a 4x4 block at (4*yh(n), 4*xh(n)) of the
// 32x32 grid; element t within chunk is (dy(t), dx(t)). Grid point (y,x)
// maps to image pixel (7y, 7x) since ih = arange(32)*224//32 = 7*arange(32).
//
// LS solve decouples by parity of the basis (t symmetric around 0):
//   [S6 S4; S4 S2] [a3; a1] = [Σt³y; Σty]   (cubic, linear)
//   [S4 S2; S2 16] [a2; a0] = [Σt²y; Σy ]   (quad, const)
// Residual SS = Σy² - aᵀ(Tᵀy)  (exact for the LS solution).

#define BATCH 256
#define NCHUNK 64
#define HW 224

__global__ __launch_bounds__(64) void retina_kernel(const float* __restrict__ x,
                                                    float* __restrict__ out) {
    int tid = blockIdx.x * blockDim.x + threadIdx.x;   // 0 .. 16383
    if (tid >= BATCH * NCHUNK) return;
    int b = tid >> 6;
    int n = tid & 63;
    // deinterleave chunk index: even bits -> xh, odd bits -> yh
    int xh = (n & 1) | ((n >> 1) & 2) | ((n >> 2) & 4);
    int yh = ((n >> 1) & 1) | ((n >> 2) & 2) | ((n >> 3) & 4);
    const float* __restrict__ xb = x + (size_t)b * 3 * HW * HW;

    float s0[3] = {0.f, 0.f, 0.f};  // Σ y
    float s1[3] = {0.f, 0.f, 0.f};  // Σ t y
    float s2[3] = {0.f, 0.f, 0.f};  // Σ t² y
    float s3[3] = {0.f, 0.f, 0.f};  // Σ t³ y
    float sq[3] = {0.f, 0.f, 0.f};  // Σ y²

#pragma unroll
    for (int t = 0; t < 16; ++t) {
        int dx = (t & 1) | ((t >> 1) & 2);        // bits 0,2 of t
        int dy = ((t >> 1) & 1) | ((t >> 2) & 2); // bits 1,3 of t
        int h = 7 * (4 * yh + dy);
        int w = 7 * (4 * xh + dx);
        int off = h * HW + w;
        float tt = -1.0f + (2.0f / 15.0f) * (float)t;
        float t2 = tt * tt;
        float t3 = t2 * tt;
#pragma unroll
        for (int c = 0; c < 3; ++c) {
            float v = xb[c * (HW * HW) + off];
            s0[c] += v;
            s1[c] += tt * v;
            s2[c] += t2 * v;
            s3[c] += t3 * v;
            sq[c] += v * v;
        }
    }

    const float S0f = 16.0f;
    const float S2f = 1360.0f / 225.0f;          // Σ t²
    const float S4f = 206992.0f / 50625.0f;      // Σ t⁴
    const float S6f = 37308880.0f / 11390625.0f; // Σ t⁶
    const float inv_det_odd  = 1.0f / (S6f * S2f - S4f * S4f);
    const float inv_det_even = 1.0f / (S4f * S0f - S2f * S2f);

    float m0 = 0.f, m1 = 0.f, m2 = 0.f, m3 = 0.f, ms = 0.f;
#pragma unroll
    for (int c = 0; c < 3; ++c) {
        float a_cube = (S2f * s3[c] - S4f * s1[c]) * inv_det_odd;
        float a_lin  = (S6f * s1[c] - S4f * s3[c]) * inv_det_odd;
        float a_quad = (S0f * s2[c] - S2f * s0[c]) * inv_det_even;
        float a_cons = (S4f * s0[c] - S2f * s2[c]) * inv_det_even;
        float ss = sq[c] - (a_cube * s3[c] + a_quad * s2[c] +
                            a_lin * s1[c] + a_cons * s0[c]);
        float sig = sqrtf(fmaxf(ss, 0.0f) * (1.0f / 16.0f));
        m0 += a_cube; m1 += a_quad; m2 += a_lin; m3 += a_cons; ms += sig;
    }

    float* o = out + (size_t)tid * 5;
    const float third = 1.0f / 3.0f;
    o[0] = m0 * third;
    o[1] = m1 * third;
    o[2] = m2 * third;
    o[3] = m3 * third;
    o[4] = ms * third;
}

extern "C" void kernel_launch(void* const* d_in, const int* in_sizes, int n_in,
                              void* d_out, int out_size, void* d_ws, size_t ws_size,
                              hipStream_t stream) {
    const float* x = (const float*)d_in[0];
    float* out = (float*)d_out;
    int total = BATCH * NCHUNK;      // 16384 tokens
    int block = 64;                  // 1 wave per block -> 256 blocks over 256 CUs
    int grid = (total + block - 1) / block;
    retina_kernel<<<grid, block, 0, stream>>>(x, out);
}